// Round 2
// baseline (285.890 us; speedup 1.0000x reference)
//
#include <hip/hip_runtime.h>

// Parabolic morphological pooling: erosion (min-plus) then dilation (max-plus),
// 7x7 parabola ||z||^2 * scale_c, 'same' padding, fully fused in one kernel.
//
// Separable: (i^2+j^2)s = i^2 s + j^2 s  ->  each 2D pool = 1D horiz + 1D vert.
// Symmetric weights: min(a+w, b+w) = min(a,b)+w  -> 6 min + 3 add per output.
//
// Per block: one 64x64 output tile of one (b,c) image.
// Stages (all LDS traffic via float4 / b128):
//   S0: load X[76][80]   (rows -6..69, cols -8..71, +inf outside image)
//   S1: H-erosion  -> Hmin[76][72]  (cols -4..67)
//   S2: V-erosion  -> E[70][72]     (rows -3..66; -inf outside image), reuses sA
//   S3: H-dilation -> Hmax[70][68pad] (cols 0..63), reuses sB
//   S4: V-dilation -> out 64x64 (global float4 stores)

#define TILE 64
#define NTH  256

#define XS   80   // X row stride (floats)
#define HMS  72   // Hmin row stride
#define ES   72   // E row stride
#define HXS  68   // Hmax row stride (padded from 64: 4-row offset = 16 banks)

#define XR   76   // X/Hmin rows: tile rows -6..69  (idx = r+6)
#define ER   70   // E/Hmax rows: tile rows -3..66  (idx = r+3)

__global__ __launch_bounds__(NTH) void parapool_fused(
    const float* __restrict__ x,
    const float* __restrict__ scale_min,
    const float* __restrict__ scale_max,
    float* __restrict__ out,
    int B, int C, int H, int W)
{
    const int tilesW = W / TILE;
    const int tilesH = H / TILE;
    int blk = blockIdx.x;
    const int tx = blk % tilesW; blk /= tilesW;
    const int ty = blk % tilesH; blk /= tilesH;
    const int bc = blk;                  // b*C + c
    const int ch = bc % C;

    const float sn = scale_min[ch];
    const float sx = scale_max[ch];
    const float w1n = 1.0f*sn, w2n = 4.0f*sn, w3n = 9.0f*sn;
    const float w1x = 1.0f*sx, w2x = 4.0f*sx, w3x = 9.0f*sx;

    const float* __restrict__ xp = x   + (size_t)bc * H * W;
    float* __restrict__       op = out + (size_t)bc * H * W;
    const int r0 = ty * TILE, c0 = tx * TILE;
    const int tid = threadIdx.x;
    const float INF = __builtin_inff();

    __shared__ float sA[XR * XS];   // X (76x80), later E (70x72)
    __shared__ float sB[XR * HMS];  // Hmin (76x72), later Hmax (70x68)
    float* Xl   = sA;
    float* Hmin = sB;
    float* El   = sA;
    float* Hmax = sB;

    // ---- S0: global -> LDS, X[76][80], +inf outside image ------------------
    for (int t = tid; t < XR * 20; t += NTH) {
        const int r = t / 20, q = t - r * 20;
        const int gr = r0 - 6 + r;
        const int gc = c0 - 8 + 4 * q;
        float4 v;
        if ((unsigned)gr < (unsigned)H && (unsigned)gc < (unsigned)(W - 3)) {
            v = *(const float4*)&xp[gr * W + gc];
        } else {
            float* e = (float*)&v;
            #pragma unroll
            for (int k = 0; k < 4; ++k) {
                const int g = gc + k;
                e[k] = ((unsigned)gr < (unsigned)H && (unsigned)g < (unsigned)W)
                         ? xp[gr * W + g] : INF;
            }
        }
        *(float4*)&Xl[r * XS + 4 * q] = v;
    }
    __syncthreads();

    // ---- S1: H-erosion -> Hmin[76][72] (tile cols -4..67) ------------------
    // thread computes 4 outputs at tile cols c..c+3, c = -4 + 4g, g in 0..17
    for (int t = tid; t < XR * 18; t += NTH) {
        const int r = t / 18, g = t - r * 18;
        const float* px = &Xl[r * XS + 4 * g];     // X idx of tile col c-4
        const float4 a = *(const float4*)px;
        const float4 b = *(const float4*)(px + 4);
        const float4 cc = *(const float4*)(px + 8);
        const float xx[12] = {a.x,a.y,a.z,a.w, b.x,b.y,b.z,b.w, cc.x,cc.y,cc.z,cc.w};
        float4 o; float* oo = (float*)&o;
        #pragma unroll
        for (int m = 0; m < 4; ++m) {              // center at xx[m+4]
            const float v0 = xx[m+4];
            const float m1 = fminf(xx[m+3], xx[m+5]) + w1n;
            const float m2 = fminf(xx[m+2], xx[m+6]) + w2n;
            const float m3 = fminf(xx[m+1], xx[m+7]) + w3n;
            oo[m] = fminf(fminf(v0, m1), fminf(m2, m3));
        }
        *(float4*)&Hmin[r * HMS + 4 * g] = o;
    }
    __syncthreads();

    // ---- S2: V-erosion -> E[70][72] (tile rows -3..66), -inf mask ----------
    // 14 row-groups (5 rows each) x 18 col-groups = 252 tasks, single pass
    if (tid < 252) {
        const int rg = tid / 18, g = tid - rg * 18;
        float4 win[11];
        #pragma unroll
        for (int i = 0; i < 11; ++i)
            win[i] = *(const float4*)&Hmin[(5 * rg + i) * HMS + 4 * g];
        #pragma unroll
        for (int s = 0; s < 5; ++s) {
            const int er = -3 + 5 * rg + s;        // tile row
            const int gr = r0 + er;
            float4 o; float* oo = (float*)&o;
            #pragma unroll
            for (int m = 0; m < 4; ++m) {
                const float v0 = ((const float*)&win[s+3])[m];
                const float m1 = fminf(((const float*)&win[s+2])[m],
                                       ((const float*)&win[s+4])[m]) + w1n;
                const float m2 = fminf(((const float*)&win[s+1])[m],
                                       ((const float*)&win[s+5])[m]) + w2n;
                const float m3 = fminf(((const float*)&win[s+0])[m],
                                       ((const float*)&win[s+6])[m]) + w3n;
                float e = fminf(fminf(v0, m1), fminf(m2, m3));
                const int gc = c0 - 4 + 4 * g + m;
                const bool in = ((unsigned)gr < (unsigned)H) &&
                                ((unsigned)gc < (unsigned)W);
                oo[m] = in ? e : -INF;             // reference pads y with -inf
            }
            *(float4*)&El[(er + 3) * ES + 4 * g] = o;
        }
    }
    __syncthreads();

    // ---- S3: H-dilation -> Hmax[70][68] (tile cols 0..63) ------------------
    for (int t = tid; t < ER * 16; t += NTH) {
        const int r = t / 16, g = t - r * 16;      // out cols 4g..4g+3
        const float* pe = &El[r * ES + 4 * g];     // E idx of tile col c-4
        const float4 a = *(const float4*)pe;
        const float4 b = *(const float4*)(pe + 4);
        const float4 cc = *(const float4*)(pe + 8);
        const float xx[12] = {a.x,a.y,a.z,a.w, b.x,b.y,b.z,b.w, cc.x,cc.y,cc.z,cc.w};
        float4 o; float* oo = (float*)&o;
        #pragma unroll
        for (int m = 0; m < 4; ++m) {
            const float v0 = xx[m+4];
            const float m1 = fmaxf(xx[m+3], xx[m+5]) - w1x;
            const float m2 = fmaxf(xx[m+2], xx[m+6]) - w2x;
            const float m3 = fmaxf(xx[m+1], xx[m+7]) - w3x;
            oo[m] = fmaxf(fmaxf(v0, m1), fmaxf(m2, m3));
        }
        *(float4*)&Hmax[r * HXS + 4 * g] = o;
    }
    __syncthreads();

    // ---- S4: V-dilation -> global out (64x64), float4 stores ---------------
    // 16 row-groups (4 rows) x 16 col-groups = 256 tasks, exactly one pass
    {
        const int rg = tid / 16, g = tid & 15;
        float4 win[10];
        #pragma unroll
        for (int i = 0; i < 10; ++i)
            win[i] = *(const float4*)&Hmax[(4 * rg + i) * HXS + 4 * g];
        #pragma unroll
        for (int s = 0; s < 4; ++s) {
            float4 o; float* oo = (float*)&o;
            #pragma unroll
            for (int m = 0; m < 4; ++m) {
                const float v0 = ((const float*)&win[s+3])[m];
                const float m1 = fmaxf(((const float*)&win[s+2])[m],
                                       ((const float*)&win[s+4])[m]) - w1x;
                const float m2 = fmaxf(((const float*)&win[s+1])[m],
                                       ((const float*)&win[s+5])[m]) - w2x;
                const float m3 = fmaxf(((const float*)&win[s+0])[m],
                                       ((const float*)&win[s+6])[m]) - w3x;
                oo[m] = fmaxf(fmaxf(v0, m1), fmaxf(m2, m3));
            }
            *(float4*)&op[(size_t)(r0 + 4 * rg + s) * W + (c0 + 4 * g)] = o;
        }
    }
}

extern "C" void kernel_launch(void* const* d_in, const int* in_sizes, int n_in,
                              void* d_out, int out_size, void* d_ws, size_t ws_size,
                              hipStream_t stream) {
    const float* x    = (const float*)d_in[0];
    const float* smin = (const float*)d_in[1];
    const float* smax = (const float*)d_in[2];
    float* out = (float*)d_out;

    const int C = in_sizes[1];                 // 64
    const int H = 256, W = 256;
    const int B = in_sizes[0] / (C * H * W);   // 8

    const int tiles = (H / TILE) * (W / TILE);
    dim3 grid(B * C * tiles);
    parapool_fused<<<grid, NTH, 0, stream>>>(x, smin, smax, out, B, C, H, W);
}

// Round 4
// 250.224 us; speedup vs baseline: 1.1425x; 1.1425x over previous
//
#include <hip/hip_runtime.h>

// Parabolic morphological pooling: min-plus erosion then max-plus dilation,
// 7x7 parabola ||z||^2 * scale_c, 'same' padding. Register-streaming design:
//
//   - One wave (64 lanes) owns a full 256-wide image row: lane l holds cols
//     4l..4l+3 as a float4.
//   - Rows are streamed top->bottom. Vertical passes = per-lane rolling 7-row
//     register windows (hw for Hmin, mw for Hmax). Horizontal passes = 6
//     scalar __shfl (+-1 lane) per row. NO LDS tiles, NO __syncthreads.
//   - 6-row-deep software pipeline:
//       X row gr -> Hmin[gr] -> (window) -> E[gr-3] -> Hmax[gr-3] ->
//       (window) -> out[gr-6]
//   - Rows/cols outside the image: +inf for erosion input, -inf for the
//     erosion output (reference pads y with the max-plus identity).
//
// Expression tree per output matches round-2 kernel exactly (absmax was 0.0):
//   o = agg(agg(v0, agg(a1,b1)+-w1), agg(agg(a2,b2)+-w2, agg(a3,b3)+-w3))

#define ROWS 32
#define HH   256
#define WW   256
#define NTH  256

__device__ __forceinline__ float4 f4s(float v) { return float4{v, v, v, v}; }

__device__ __forceinline__ float4 f4min(float4 a, float4 b) {
    return float4{fminf(a.x,b.x), fminf(a.y,b.y), fminf(a.z,b.z), fminf(a.w,b.w)};
}
__device__ __forceinline__ float4 f4max(float4 a, float4 b) {
    return float4{fmaxf(a.x,b.x), fmaxf(a.y,b.y), fmaxf(a.z,b.z), fmaxf(a.w,b.w)};
}
__device__ __forceinline__ float4 f4add(float4 a, float s) {
    return float4{a.x+s, a.y+s, a.z+s, a.w+s};
}

// horizontal pass: window cols c-3..c+3 from own float4 + 3 words each side
template<bool IS_MIN>
__device__ __forceinline__ float4 hpass(float4 v, float w1, float w2, float w3,
                                        int lane) {
    const float EDGE = IS_MIN ? __builtin_inff() : -__builtin_inff();
    float ly = __shfl_up(v.y, 1, 64);
    float lz = __shfl_up(v.z, 1, 64);
    float lw = __shfl_up(v.w, 1, 64);
    float rx = __shfl_down(v.x, 1, 64);
    float ry = __shfl_down(v.y, 1, 64);
    float rz = __shfl_down(v.z, 1, 64);
    if (lane == 0)  { ly = EDGE; lz = EDGE; lw = EDGE; }
    if (lane == 63) { rx = EDGE; ry = EDGE; rz = EDGE; }
    const float win[10] = {ly, lz, lw, v.x, v.y, v.z, v.w, rx, ry, rz};
    float o[4];
#pragma unroll
    for (int m = 0; m < 4; ++m) {
        const float v0 = win[m+3];
        if (IS_MIN) {
            const float m1 = fminf(win[m+2], win[m+4]) + w1;
            const float m2 = fminf(win[m+1], win[m+5]) + w2;
            const float m3 = fminf(win[m],   win[m+6]) + w3;
            o[m] = fminf(fminf(v0, m1), fminf(m2, m3));
        } else {
            const float m1 = fmaxf(win[m+2], win[m+4]) - w1;
            const float m2 = fmaxf(win[m+1], win[m+5]) - w2;
            const float m3 = fmaxf(win[m],   win[m+6]) - w3;
            o[m] = fmaxf(fmaxf(v0, m1), fmaxf(m2, m3));
        }
    }
    return float4{o[0], o[1], o[2], o[3]};
}

// vertical pass over a 7-row register window (w[3] = center row)
template<bool IS_MIN>
__device__ __forceinline__ float4 vpass(const float4 w[7], float w1, float w2,
                                        float w3) {
    if (IS_MIN) {
        const float4 m1 = f4add(f4min(w[2], w[4]),  w1);
        const float4 m2 = f4add(f4min(w[1], w[5]),  w2);
        const float4 m3 = f4add(f4min(w[0], w[6]),  w3);
        return f4min(f4min(w[3], m1), f4min(m2, m3));
    } else {
        const float4 m1 = f4add(f4max(w[2], w[4]), -w1);
        const float4 m2 = f4add(f4max(w[1], w[5]), -w2);
        const float4 m3 = f4add(f4max(w[0], w[6]), -w3);
        return f4max(f4max(w[3], m1), f4max(m2, m3));
    }
}

__device__ __forceinline__ float4 loadrow(const float* __restrict__ xp, int gr,
                                          int lane) {
    if ((unsigned)gr < (unsigned)HH)
        return *(const float4*)&xp[gr * WW + lane * 4];
    return f4s(__builtin_inff());          // erosion identity outside image
}

__global__ __launch_bounds__(NTH) void parapool_stream(
    const float* __restrict__ x,
    const float* __restrict__ scale_min,
    const float* __restrict__ scale_max,
    float* __restrict__ out, int C)
{
    const int lane = threadIdx.x & 63;
    const int wv   = threadIdx.x >> 6;
    const int gid  = blockIdx.x * 4 + wv;     // strip id; block = 4 adjacent strips
    const int sPerImg = HH / ROWS;            // 8
    const int bc = gid / sPerImg;
    const int st = gid - bc * sPerImg;
    const int ch = bc % C;
    const int rs = st * ROWS;

    const float sn = scale_min[ch];
    const float sx = scale_max[ch];
    const float w1n = 1.0f*sn, w2n = 4.0f*sn, w3n = 9.0f*sn;
    const float w1x = 1.0f*sx, w2x = 4.0f*sx, w3x = 9.0f*sx;

    const float* __restrict__ xp = x   + (size_t)bc * (HH * WW);
    float* __restrict__       op = out + (size_t)bc * (HH * WW);

    const float INF = __builtin_inff();
    float4 hw[7], mw[7];                      // Hmin / Hmax rolling windows
#pragma unroll
    for (int k = 0; k < 7; ++k) { hw[k] = f4s(INF); mw[k] = f4s(-INF); }

    float4 xnext = loadrow(xp, rs - 6, lane);

#pragma unroll 2
    for (int it = 0; it < ROWS + 12; ++it) {
        const int gr = rs - 6 + it;           // current X row
        const float4 xv = xnext;
        xnext = loadrow(xp, gr + 1, lane);    // prefetch next row

        // H-erosion of row gr -> push into hw
        const float4 hm = hpass<true>(xv, w1n, w2n, w3n, lane);
#pragma unroll
        for (int k = 0; k < 6; ++k) hw[k] = hw[k+1];
        hw[6] = hm;

        // V-erosion -> E row er (= -inf outside image), then H-dilation
        const int er = gr - 3;
        float4 E;
        if ((unsigned)er < (unsigned)HH)
            E = vpass<true>(hw, w1n, w2n, w3n);
        else
            E = f4s(-INF);
        const float4 hx = hpass<false>(E, w1x, w2x, w3x, lane);
#pragma unroll
        for (int k = 0; k < 6; ++k) mw[k] = mw[k+1];
        mw[6] = hx;

        // V-dilation -> out row gr-6 (valid once both windows are warm)
        if (it >= 12) {
            const float4 o = vpass<false>(mw, w1x, w2x, w3x);
            *(float4*)&op[(gr - 6) * WW + lane * 4] = o;
        }
    }
}

extern "C" void kernel_launch(void* const* d_in, const int* in_sizes, int n_in,
                              void* d_out, int out_size, void* d_ws, size_t ws_size,
                              hipStream_t stream) {
    const float* x    = (const float*)d_in[0];
    const float* smin = (const float*)d_in[1];
    const float* smax = (const float*)d_in[2];
    float* out = (float*)d_out;

    const int C = in_sizes[1];                    // 64
    const int B = in_sizes[0] / (C * HH * WW);    // 8

    const int totalStrips = B * C * (HH / ROWS);  // 4096
    dim3 grid(totalStrips / 4);                   // 1024 blocks x 4 waves
    parapool_stream<<<grid, NTH, 0, stream>>>(x, smin, smax, out, C);
}

// Round 6
// 248.803 us; speedup vs baseline: 1.1491x; 1.0057x over previous
//
#include <hip/hip_runtime.h>

// Parabolic morphological pooling: min-plus erosion then max-plus dilation,
// 7x7 parabola ||z||^2 * scale_c, 'same' padding. Register-streaming design:
//
//   - One wave (64 lanes) owns a full 256-wide image row: lane l holds cols
//     4l..4l+3 as a float4.
//   - Rows streamed top->bottom; vertical passes = per-lane rolling 7-row
//     register windows; horizontal passes = 6 scalar __shfl per row.
//     NO LDS tiles, NO __syncthreads.
//   - 6-row-deep software pipeline:
//       X row gr -> Hmin[gr] -> (window) -> E[gr-3] -> Hmax[gr-3] ->
//       (window) -> out[gr-6]
//   - FULL UNROLL of the 44-trip stream loop: window shifts become register
//     renaming (kills ~48 v_mov/iter), warm-up guards (it<6: vpass/dilation
//     results provably dead) constant-fold to skipped code.
//
// min/max combines are chained (not tree) to allow v_min3/v_max3 fusion —
// exact for min/max (associative; no NaNs here), so absmax stays 0.0.

#define ROWS 32
#define HH   256
#define WW   256
#define NTH  256

__device__ __forceinline__ float4 f4s(float v) { return float4{v, v, v, v}; }

__device__ __forceinline__ float4 f4min(float4 a, float4 b) {
    return float4{fminf(a.x,b.x), fminf(a.y,b.y), fminf(a.z,b.z), fminf(a.w,b.w)};
}
__device__ __forceinline__ float4 f4max(float4 a, float4 b) {
    return float4{fmaxf(a.x,b.x), fmaxf(a.y,b.y), fmaxf(a.z,b.z), fmaxf(a.w,b.w)};
}
__device__ __forceinline__ float4 f4add(float4 a, float s) {
    return float4{a.x+s, a.y+s, a.z+s, a.w+s};
}

// horizontal pass: window cols c-3..c+3 from own float4 + 3 words each side
template<bool IS_MIN>
__device__ __forceinline__ float4 hpass(float4 v, float w1, float w2, float w3,
                                        int lane) {
    const float EDGE = IS_MIN ? __builtin_inff() : -__builtin_inff();
    float ly = __shfl_up(v.y, 1, 64);
    float lz = __shfl_up(v.z, 1, 64);
    float lw = __shfl_up(v.w, 1, 64);
    float rx = __shfl_down(v.x, 1, 64);
    float ry = __shfl_down(v.y, 1, 64);
    float rz = __shfl_down(v.z, 1, 64);
    if (lane == 0)  { ly = EDGE; lz = EDGE; lw = EDGE; }
    if (lane == 63) { rx = EDGE; ry = EDGE; rz = EDGE; }
    const float win[10] = {ly, lz, lw, v.x, v.y, v.z, v.w, rx, ry, rz};
    float o[4];
#pragma unroll
    for (int m = 0; m < 4; ++m) {
        const float v0 = win[m+3];
        if (IS_MIN) {
            const float m1 = fminf(win[m+2], win[m+4]) + w1;
            const float m2 = fminf(win[m+1], win[m+5]) + w2;
            const float m3 = fminf(win[m],   win[m+6]) + w3;
            o[m] = fminf(fminf(fminf(v0, m1), m2), m3);   // chain -> v_min3
        } else {
            const float m1 = fmaxf(win[m+2], win[m+4]) - w1;
            const float m2 = fmaxf(win[m+1], win[m+5]) - w2;
            const float m3 = fmaxf(win[m],   win[m+6]) - w3;
            o[m] = fmaxf(fmaxf(fmaxf(v0, m1), m2), m3);   // chain -> v_max3
        }
    }
    return float4{o[0], o[1], o[2], o[3]};
}

// vertical pass over a 7-row register window (w[3] = center row)
template<bool IS_MIN>
__device__ __forceinline__ float4 vpass(const float4 w[7], float w1, float w2,
                                        float w3) {
    if (IS_MIN) {
        const float4 m1 = f4add(f4min(w[2], w[4]),  w1);
        const float4 m2 = f4add(f4min(w[1], w[5]),  w2);
        const float4 m3 = f4add(f4min(w[0], w[6]),  w3);
        return f4min(f4min(f4min(w[3], m1), m2), m3);
    } else {
        const float4 m1 = f4add(f4max(w[2], w[4]), -w1);
        const float4 m2 = f4add(f4max(w[1], w[5]), -w2);
        const float4 m3 = f4add(f4max(w[0], w[6]), -w3);
        return f4max(f4max(f4max(w[3], m1), m2), m3);
    }
}

__device__ __forceinline__ float4 loadrow(const float* __restrict__ xp, int gr,
                                          int lane) {
    if ((unsigned)gr < (unsigned)HH)
        return *(const float4*)&xp[gr * WW + lane * 4];
    return f4s(__builtin_inff());          // erosion identity outside image
}

__global__ __launch_bounds__(NTH, 4) void parapool_stream(
    const float* __restrict__ x,
    const float* __restrict__ scale_min,
    const float* __restrict__ scale_max,
    float* __restrict__ out, int C)
{
    const int lane = threadIdx.x & 63;
    const int wv   = threadIdx.x >> 6;
    const int gid  = blockIdx.x * 4 + wv;     // strip id; block = 4 adjacent strips
    const int sPerImg = HH / ROWS;            // 8
    const int bc = gid / sPerImg;
    const int st = gid - bc * sPerImg;
    const int ch = bc % C;
    const int rs = st * ROWS;

    const float sn = scale_min[ch];
    const float sx = scale_max[ch];
    const float w1n = 1.0f*sn, w2n = 4.0f*sn, w3n = 9.0f*sn;
    const float w1x = 1.0f*sx, w2x = 4.0f*sx, w3x = 9.0f*sx;

    const float* __restrict__ xp = x   + (size_t)bc * (HH * WW);
    float* __restrict__       op = out + (size_t)bc * (HH * WW);

    const float INF = __builtin_inff();
    float4 hw[7], mw[7];                      // Hmin / Hmax rolling windows
#pragma unroll
    for (int k = 0; k < 7; ++k) { hw[k] = f4s(INF); mw[k] = f4s(-INF); }

    // Fully-unrolled 6-row-deep pipeline. After unrolling, the it<6 / it<12
    // guards are compile-time and the window shifts are register renames.
#pragma unroll
    for (int it = 0; it < ROWS + 12; ++it) {
        const int gr = rs - 6 + it;           // current X row
        const float4 xv = loadrow(xp, gr, lane);

        // H-erosion of row gr -> push into hw
        const float4 hm = hpass<true>(xv, w1n, w2n, w3n, lane);
#pragma unroll
        for (int k = 0; k < 6; ++k) hw[k] = hw[k+1];
        hw[6] = hm;

        if (it >= 6) {                        // earlier E rows are never used
            // V-erosion -> E row er (-inf outside image), then H-dilation
            const int er = gr - 3;
            float4 E;
            if ((unsigned)er < (unsigned)HH)
                E = vpass<true>(hw, w1n, w2n, w3n);
            else
                E = f4s(-INF);
            const float4 hx = hpass<false>(E, w1x, w2x, w3x, lane);
#pragma unroll
            for (int k = 0; k < 6; ++k) mw[k] = mw[k+1];
            mw[6] = hx;

            // V-dilation -> out row gr-6 (valid once both windows are warm)
            if (it >= 12) {
                const float4 o = vpass<false>(mw, w1x, w2x, w3x);
                *(float4*)&op[(gr - 6) * WW + lane * 4] = o;
            }
        }
    }
}

extern "C" void kernel_launch(void* const* d_in, const int* in_sizes, int n_in,
                              void* d_out, int out_size, void* d_ws, size_t ws_size,
                              hipStream_t stream) {
    const float* x    = (const float*)d_in[0];
    const float* smin = (const float*)d_in[1];
    const float* smax = (const float*)d_in[2];
    float* out = (float*)d_out;

    const int C = in_sizes[1];                    // 64
    const int B = in_sizes[0] / (C * HH * WW);    // 8

    const int totalStrips = B * C * (HH / ROWS);  // 4096
    dim3 grid(totalStrips / 4);                   // 1024 blocks x 4 waves
    parapool_stream<<<grid, NTH, 0, stream>>>(x, smin, smax, out, C);
}